// Round 8
// baseline (507.697 us; speedup 1.0000x reference)
//
#include <hip/hip_runtime.h>

#define B_  8
#define C_  128
#define H_  128
#define W_  256
#define HW_ (H_ * W_)
#define TH  8
#define TW  32
#define NPAIR 4                    // channel-pairs per stage (8 channels)
#define ROWD 48                    // dwords per f2 row (12 phys units of 16B)
#define PAIRN (16 * ROWD)          // 768 dwords per pair-tile (16 rows)
#define PU(u) ((u) + ((u) >> 3))   // gap layout: unit -> phys unit
#define NTHREADS 576

typedef __fp16 h2 __attribute__((ext_vector_type(2)));

__device__ __forceinline__ float dot2f16(unsigned int a, unsigned int b, float c) {
#if __has_builtin(__builtin_amdgcn_fdot2)
    return __builtin_amdgcn_fdot2(__builtin_bit_cast(h2, a),
                                  __builtin_bit_cast(h2, b), c, false);
#else
    h2 ha = __builtin_bit_cast(h2, a), hb = __builtin_bit_cast(h2, b);
    return c + (float)ha.x * (float)hb.x + (float)ha.y * (float)hb.y;
#endif
}

__device__ __forceinline__ unsigned int pk(float x, float y) {
    h2 r = __builtin_amdgcn_cvt_pkrtz(x, y);
    return __builtin_bit_cast(unsigned int, r);
}

// 9-wave block, wave = di, tile 8x32, lane = (row hh, 4-px strip sc).
// LDS: f2 ONLY, 2 buffers x 4 pair-tiles; f1 comes straight from global into
// each lane's registers (its own strip; 9x redundancy absorbed by L1/L2).
// Stage = 8 channels. Depth-1.5 pipeline: stage s+1 loads issued before
// compute of stage s; STOREST waits only its own loads (counted vmcnt);
// barrier = lgkmcnt(0) + raw s_barrier (no vmcnt drain).
__global__ __launch_bounds__(NTHREADS, 3) void cv_kernel(
    const float* __restrict__ f1g, const float* __restrict__ f2g,
    float* __restrict__ outg) {
    __shared__ __align__(16) unsigned int lds[2][NPAIR * PAIRN];

    const int tid = threadIdx.x;
    const int w0 = blockIdx.x * TW;
    const int h0 = blockIdx.y * TH;
    const int b  = blockIdx.z;

    // ---- f2 staging slots: 4 pairs x 16 rows x 10 units = 640 slots ----
    // slot A = tid (all 576); slot B = 576 + tid for tid < 64.
    int offA, ldA, offB = 0, ldB = 0;
    float mA, mB = 0.f;
    const bool dual = (tid < 64);
    {
        int s = tid;
        int pp = s / 160, rem = s % 160;
        int r = rem / 10, cu = rem % 10;
        int gh = h0 - 4 + r, gw = w0 - 4 + 4 * cu;
        bool valid = (gh >= 0) && (gh < H_) && (gw >= 0) && (gw <= W_ - 4);
        int ghc = min(max(gh, 0), H_ - 1);
        int gwc = min(max(gw, 0), W_ - 4);
        offA = ((b * C_ + 2 * pp) * H_ + ghc) * W_ + gwc;
        ldA  = pp * PAIRN + r * ROWD + 4 * PU(cu);
        mA   = valid ? 1.f : 0.f;
    }
    if (dual) {
        int s = 576 + tid;
        int pp = s / 160, rem = s % 160;
        int r = rem / 10, cu = rem % 10;
        int gh = h0 - 4 + r, gw = w0 - 4 + 4 * cu;
        bool valid = (gh >= 0) && (gh < H_) && (gw >= 0) && (gw <= W_ - 4);
        int ghc = min(max(gh, 0), H_ - 1);
        int gwc = min(max(gw, 0), W_ - 4);
        offB = ((b * C_ + 2 * pp) * H_ + ghc) * W_ + gwc;
        ldB  = pp * PAIRN + r * ROWD + 4 * PU(cu);
        mB   = valid ? 1.f : 0.f;
    }

#define LOADST()                                                              \
    do {                                                                      \
        aA = *(const float4*)(f2g + offA);                                    \
        bA = *(const float4*)(f2g + offA + HW_);                              \
        offA += 8 * HW_;                                                      \
        if (dual) {                                                           \
            aB = *(const float4*)(f2g + offB);                                \
            bB = *(const float4*)(f2g + offB + HW_);                          \
            offB += 8 * HW_;                                                  \
        }                                                                     \
    } while (0)

#define STOREST(bi)                                                           \
    do {                                                                      \
        uint4 wv;                                                             \
        wv.x = pk(aA.x * mA, bA.x * mA);                                      \
        wv.y = pk(aA.y * mA, bA.y * mA);                                      \
        wv.z = pk(aA.z * mA, bA.z * mA);                                      \
        wv.w = pk(aA.w * mA, bA.w * mA);                                      \
        *(uint4*)(&lds[bi][ldA]) = wv;                                        \
        if (dual) {                                                           \
            uint4 w2;                                                         \
            w2.x = pk(aB.x * mB, bB.x * mB);                                  \
            w2.y = pk(aB.y * mB, bB.y * mB);                                  \
            w2.z = pk(aB.z * mB, bB.z * mB);                                  \
            w2.w = pk(aB.w * mB, bB.w * mB);                                  \
            *(uint4*)(&lds[bi][ldB]) = w2;                                    \
        }                                                                     \
    } while (0)

#define BAR()                                                                 \
    do {                                                                      \
        asm volatile("s_waitcnt lgkmcnt(0)" ::: "memory");                    \
        __builtin_amdgcn_s_barrier();                                         \
    } while (0)

    // ---- compute mapping ----
    const int di   = tid >> 6;        // 0..8
    const int lane = tid & 63;
    const int hh   = lane >> 3;       // 0..7
    const int sc   = lane & 7;        // 0..7, 4-px strip
    int rdm[3];
#pragma unroll
    for (int m = 0; m < 3; ++m)
        rdm[m] = (hh + di) * ROWD + 4 * PU(sc + m);
    int off1 = (b * C_ * H_ + h0 + hh) * W_ + w0 + 4 * sc;  // f1, channel 0

    float acc[9][4];
#pragma unroll
    for (int j = 0; j < 9; ++j)
#pragma unroll
        for (int p = 0; p < 4; ++p) acc[j][p] = 0.f;

#define COMPUTE(bi)                                                           \
    do {                                                                      \
        _Pragma("unroll")                                                     \
        for (int q = 0; q < NPAIR; ++q) {                                     \
            float4 x = *(const float4*)(f1g + off1 + (2 * q) * HW_);          \
            float4 y = *(const float4*)(f1g + off1 + (2 * q + 1) * HW_);      \
            const unsigned int* buf = &lds[bi][q * PAIRN];                    \
            uint4 fa = *(const uint4*)(buf + rdm[0]);                         \
            uint4 fb = *(const uint4*)(buf + rdm[1]);                         \
            uint4 fc = *(const uint4*)(buf + rdm[2]);                         \
            unsigned int fy[4];                                               \
            fy[0] = pk(x.x, y.x);                                             \
            fy[1] = pk(x.y, y.y);                                             \
            fy[2] = pk(x.z, y.z);                                             \
            fy[3] = pk(x.w, y.w);                                             \
            unsigned int f2u[12] = {fa.x, fa.y, fa.z, fa.w, fb.x, fb.y,       \
                                    fb.z, fb.w, fc.x, fc.y, fc.z, fc.w};      \
            _Pragma("unroll")                                                 \
            for (int j = 0; j < 9; ++j)                                       \
                _Pragma("unroll")                                             \
                for (int p = 0; p < 4; ++p)                                   \
                    acc[j][p] = dot2f16(fy[p], f2u[p + j], acc[j][p]);        \
        }                                                                     \
        off1 += 2 * NPAIR * HW_;                                              \
    } while (0)

    float4 aA, bA, aB, bB;

    // prologue: stage 0 loads -> LDS buf0
    LOADST();
    STOREST(0);
    BAR();

    // 16 stages total; unroll-2 keeps buffer index compile-time
    for (int st = 0; st < 14; st += 2) {
        LOADST();                    // stage st+1 loads (in flight over compute)
        COMPUTE(0);                  // stage st
        STOREST(1);                  // stage st+1 (counted vmcnt)
        BAR();
        LOADST();                    // stage st+2
        COMPUTE(1);                  // stage st+1
        STOREST(0);                  // stage st+2
        BAR();
    }
    LOADST();                        // stage 15
    COMPUTE(0);                      // stage 14
    STOREST(1);                      // stage 15
    BAR();
    COMPUTE(1);                      // stage 15

    // ---- epilogue: mean over C and store ----
    const float inv = 1.0f / 128.0f;
    int obase = ((b * 81 + di * 9) * H_ + h0 + hh) * W_ + w0 + 4 * sc;
#pragma unroll
    for (int j = 0; j < 9; ++j) {
        float4 o = make_float4(acc[j][0] * inv, acc[j][1] * inv,
                               acc[j][2] * inv, acc[j][3] * inv);
        *(float4*)(outg + obase) = o;
        obase += HW_;
    }
}

extern "C" void kernel_launch(void* const* d_in, const int* in_sizes, int n_in,
                              void* d_out, int out_size, void* d_ws, size_t ws_size,
                              hipStream_t stream) {
    const float* f1 = (const float*)d_in[0];
    const float* f2 = (const float*)d_in[1];
    float* out = (float*)d_out;
    dim3 grid(W_ / TW, H_ / TH, B_);   // 8 x 16 x 8 = 1024 blocks
    cv_kernel<<<grid, NTHREADS, 0, stream>>>(f1, f2, out);
}

// Round 9
// 124.293 us; speedup vs baseline: 4.0847x; 4.0847x over previous
//
#include <hip/hip_runtime.h>

#define B_  8
#define C_  128
#define H_  128
#define W_  256
#define HW_ (H_ * W_)
#define TH  8
#define TW  32
#define NPAIR 4                    // channel-pairs per stage (8 channels/stage)
#define F2RS 72                    // f2 row stride (dwords) = 288B -> 32-bank row offset
#define F2PT (16 * F2RS)           // 1152 dw per f2 pair-tile (16 rows)
#define F1RS 36                    // f1 row stride (dwords) = 144B
#define F1PT (8 * F1RS)            // 288 dw per f1 pair-tile (8 rows)
#define F1OFF (NPAIR * F2PT)       // 4608
#define BUFN (F1OFF + NPAIR * F1PT) // 5760 dw per buffer (22.5 KB)
#define NTHREADS 576

typedef __fp16 h2 __attribute__((ext_vector_type(2)));

__device__ __forceinline__ float dot2f16(unsigned int a, unsigned int b, float c) {
#if __has_builtin(__builtin_amdgcn_fdot2)
    return __builtin_amdgcn_fdot2(__builtin_bit_cast(h2, a),
                                  __builtin_bit_cast(h2, b), c, false);
#else
    h2 ha = __builtin_bit_cast(h2, a), hb = __builtin_bit_cast(h2, b);
    return c + (float)ha.x * (float)hb.x + (float)ha.y * (float)hb.y;
#endif
}

__device__ __forceinline__ unsigned int pk(float x, float y) {
    h2 r = __builtin_amdgcn_cvt_pkrtz(x, y);
    return __builtin_bit_cast(unsigned int, r);
}

// 9-wave block, wave = di, tile 8x32, lane = (row hh, 4-px strip sc).
// r6-proven skeleton: LDS-only COMPUTE, <=4 staged float4/thread,
// bounds(576,3), depth-1.5 pipeline with raw s_barrier + lgkmcnt(0).
// New: bank-exact LDS layout (all ds_read/ds_write 8-lane groups cover
// 32 banks), 8 channels/stage -> 16 barrier-stages.
// Staging roles: tid<512 f2 primary (u=tid&7); tid<128 also f2 u=8,9;
// tid 128..383 also f1; wave 8 computes only.
__global__ __launch_bounds__(NTHREADS, 3) void cv_kernel(
    const float* __restrict__ f1g, const float* __restrict__ f2g,
    float* __restrict__ outg) {
    __shared__ __align__(16) unsigned int lds[2][BUFN];

    const int tid = threadIdx.x;
    const int w0 = blockIdx.x * TW;
    const int h0 = blockIdx.y * TH;
    const int b  = blockIdx.z;

    // ---- slot A: f2 primary, 4 pairs x 16 rows x units 0..7 = 512 slots ----
    const bool roleA = (tid < 512);
    int offA = 0, ldA = 0;
    float mA = 0.f;
    if (roleA) {
        int pp = tid >> 7, r = (tid >> 3) & 15, u = tid & 7;
        int gh = h0 - 4 + r, gw = w0 - 4 + 4 * u;
        bool valid = (gh >= 0) && (gh < H_) && (gw >= 0) && (gw <= W_ - 4);
        int ghc = min(max(gh, 0), H_ - 1);
        int gwc = min(max(gw, 0), W_ - 4);
        offA = ((b * C_ + 2 * pp) * H_ + ghc) * W_ + gwc;
        ldA  = pp * F2PT + r * F2RS + 4 * u;
        mA   = valid ? 1.f : 0.f;
    }
    // ---- slot C: tid<128 -> f2 units 8,9 (4pp x 8 r-pairs... exact map below);
    //              tid 128..383 -> f1 (4 pairs x 8 rows x 8 units) ----
    const bool roleC = (tid < 384);
    int offC = 0, ldC = 0;
    float mC = 0.f;
    const float* pC = f1g;
    if (tid < 128) {               // f2 u89: pp = tid>>5, r = (tid>>1)&15, u = 8+(tid&1)
        int pp = tid >> 5, r = (tid >> 1) & 15, u = 8 + (tid & 1);
        int gh = h0 - 4 + r, gw = w0 - 4 + 4 * u;
        bool valid = (gh >= 0) && (gh < H_) && (gw >= 0) && (gw <= W_ - 4);
        int ghc = min(max(gh, 0), H_ - 1);
        int gwc = min(max(gw, 0), W_ - 4);
        offC = ((b * C_ + 2 * pp) * H_ + ghc) * W_ + gwc;
        pC   = f2g;
        ldC  = pp * F2PT + r * F2RS + 4 * u;
        mC   = valid ? 1.f : 0.f;
    } else if (tid < 384) {        // f1: pp = t>>6, r = (t>>3)&7, u = t&7
        int t = tid - 128;
        int pp = t >> 6, r = (t >> 3) & 7, u = t & 7;
        offC = ((b * C_ + 2 * pp) * H_ + h0 + r) * W_ + w0 + 4 * u;
        pC   = f1g;
        ldC  = F1OFF + pp * F1PT + r * F1RS + 4 * u;
        mC   = 1.f;
    }

#define LOADST()                                                              \
    do {                                                                      \
        if (roleA) {                                                          \
            aA = *(const float4*)(f2g + offA);                                \
            bA = *(const float4*)(f2g + offA + HW_);                          \
            offA += 8 * HW_;                                                  \
        }                                                                     \
        if (roleC) {                                                          \
            cC = *(const float4*)(pC + offC);                                 \
            dC = *(const float4*)(pC + offC + HW_);                           \
            offC += 8 * HW_;                                                  \
        }                                                                     \
    } while (0)

#define STOREST(bi)                                                           \
    do {                                                                      \
        if (roleA) {                                                          \
            uint4 wv;                                                         \
            wv.x = pk(aA.x * mA, bA.x * mA);                                  \
            wv.y = pk(aA.y * mA, bA.y * mA);                                  \
            wv.z = pk(aA.z * mA, bA.z * mA);                                  \
            wv.w = pk(aA.w * mA, bA.w * mA);                                  \
            *(uint4*)(&lds[bi][ldA]) = wv;                                    \
        }                                                                     \
        if (roleC) {                                                          \
            uint4 w2;                                                         \
            w2.x = pk(cC.x * mC, dC.x * mC);                                  \
            w2.y = pk(cC.y * mC, dC.y * mC);                                  \
            w2.z = pk(cC.z * mC, dC.z * mC);                                  \
            w2.w = pk(cC.w * mC, dC.w * mC);                                  \
            *(uint4*)(&lds[bi][ldC]) = w2;                                    \
        }                                                                     \
    } while (0)

#define BAR()                                                                 \
    do {                                                                      \
        asm volatile("s_waitcnt lgkmcnt(0)" ::: "memory");                    \
        __builtin_amdgcn_s_barrier();                                         \
    } while (0)

    // ---- compute mapping ----
    const int di   = tid >> 6;       // 0..8
    const int lane = tid & 63;
    const int hh   = lane >> 3;      // 0..7
    const int sc   = lane & 7;       // 0..7, 4-px strip
    const int rd0  = (hh + di) * F2RS + 4 * sc;          // f2 units sc..sc+2
    const int rf0  = F1OFF + hh * F1RS + 4 * sc;         // f1 unit sc

    float acc[9][4];
#pragma unroll
    for (int j = 0; j < 9; ++j)
#pragma unroll
        for (int p = 0; p < 4; ++p) acc[j][p] = 0.f;

#define COMPUTE(bi)                                                           \
    do {                                                                      \
        _Pragma("unroll 2")                                                   \
        for (int q = 0; q < NPAIR; ++q) {                                     \
            const unsigned int* bf2 = &lds[bi][q * F2PT];                     \
            const unsigned int* bf1 = &lds[bi][q * F1PT];                     \
            uint4 fa = *(const uint4*)(bf2 + rd0);                            \
            uint4 fb = *(const uint4*)(bf2 + rd0 + 4);                        \
            uint4 fc = *(const uint4*)(bf2 + rd0 + 8);                        \
            uint4 ga = *(const uint4*)(bf1 + rf0);                            \
            unsigned int f2u[12] = {fa.x, fa.y, fa.z, fa.w, fb.x, fb.y,       \
                                    fb.z, fb.w, fc.x, fc.y, fc.z, fc.w};      \
            unsigned int f1u[4]  = {ga.x, ga.y, ga.z, ga.w};                  \
            _Pragma("unroll")                                                 \
            for (int j = 0; j < 9; ++j)                                       \
                _Pragma("unroll")                                             \
                for (int p = 0; p < 4; ++p)                                   \
                    acc[j][p] = dot2f16(f1u[p], f2u[p + j], acc[j][p]);       \
        }                                                                     \
    } while (0)

    float4 aA, bA, cC, dC;

    // prologue: stage 0 -> buf0
    LOADST();
    STOREST(0);
    BAR();

    // 16 stages of 8 channels
    for (int st = 0; st < 14; st += 2) {
        LOADST();                    // stage st+1 (in flight over compute)
        COMPUTE(0);                  // stage st
        STOREST(1);                  // stage st+1 (counted vmcnt)
        BAR();
        LOADST();                    // stage st+2
        COMPUTE(1);                  // stage st+1
        STOREST(0);                  // stage st+2
        BAR();
    }
    LOADST();                        // stage 15
    COMPUTE(0);                      // stage 14
    STOREST(1);                      // stage 15
    BAR();
    COMPUTE(1);                      // stage 15

    // ---- epilogue: mean over C and store ----
    const float inv = 1.0f / 128.0f;
    int obase = ((b * 81 + di * 9) * H_ + h0 + hh) * W_ + w0 + 4 * sc;
#pragma unroll
    for (int j = 0; j < 9; ++j) {
        float4 o = make_float4(acc[j][0] * inv, acc[j][1] * inv,
                               acc[j][2] * inv, acc[j][3] * inv);
        *(float4*)(outg + obase) = o;
        obase += HW_;
    }
}

extern "C" void kernel_launch(void* const* d_in, const int* in_sizes, int n_in,
                              void* d_out, int out_size, void* d_ws, size_t ws_size,
                              hipStream_t stream) {
    const float* f1 = (const float*)d_in[0];
    const float* f2 = (const float*)d_in[1];
    float* out = (float*)d_out;
    dim3 grid(W_ / TW, H_ / TH, B_);   // 8 x 16 x 8 = 1024 blocks
    cv_kernel<<<grid, NTHREADS, 0, stream>>>(f1, f2, out);
}